// Round 8
// baseline (523.534 us; speedup 1.0000x reference)
//
#include <hip/hip_runtime.h>
#include <hip/hip_fp16.h>
#include <math.h>

// GCNII forward: N=100000, E=1.6M, F_IN=300, H=64, OUT=20, L=8
// Round 8: per-XCD privatized degree histogram (no cross-XCD atomic
// ping-pong), edge lists padded to multiples of 4 -> uint4 edge loads with
// 4-wide gather unroll in the fused layer kernel.

#define HID 64
#define FIN 300
#define NOUT 20
#define ALPHA 0.1f
#define DSCALE 262144.0f   // 2^18 fixed-point scale for weighted degree
#define CNT_SHIFT 25
#define DEG_MASK 0x1FFFFFFu

typedef _Float16 f16;
typedef f16 f16x8 __attribute__((ext_vector_type(8)));
typedef float f32x4 __attribute__((ext_vector_type(4)));

// ---- helpers -----------------------------------------------------------
__device__ __forceinline__ float wdec(unsigned v) {
    union { unsigned short u; __half h; } c;
    c.u = (unsigned short)(v >> 17);
    return __half2float(c.h);
}

__device__ __forceinline__ void unpack8(const float4& v, float* f) {
    const __half2* p = reinterpret_cast<const __half2*>(&v);
#pragma unroll
    for (int i = 0; i < 4; ++i) {
        float2 t = __half22float2(p[i]);
        f[2 * i] = t.x;
        f[2 * i + 1] = t.y;
    }
}

// ---- generic zero ------------------------------------------------------
__global__ void zero_k(unsigned* __restrict__ p, int nwords) {
    int i = blockIdx.x * blockDim.x + threadIdx.x;
    if (i < nwords) p[i] = 0u;
}

// ---- privatized histogram: one 32-bit atomic per edge into own XCD copy --
__global__ void accum_k(const int* __restrict__ col, const float* __restrict__ w,
                        unsigned* __restrict__ packed8,
                        unsigned short* __restrict__ rank16, int e, int n) {
    int i = blockIdx.x * blockDim.x + threadIdx.x;
    if (i < e) {
        int copy = blockIdx.x & 7;
        unsigned q = (unsigned)__float2uint_rn(w[i] * DSCALE);
        unsigned old = atomicAdd(&packed8[(size_t)copy * n + col[i]],
                                 (1u << CNT_SHIFT) | q);
        rank16[i] = (unsigned short)(((old >> CNT_SHIFT) & 0xFFu) | (copy << 8));
    }
}

// ---- fold 8 copies: dinv, per-copy offsets, padded counts, block sums ---
__global__ __launch_bounds__(1024) void unpackscan_k(const unsigned* __restrict__ packed8,
                                                     float* __restrict__ dinv,
                                                     unsigned char* __restrict__ off8,
                                                     int* __restrict__ padcnt,
                                                     int* __restrict__ bsum, int n) {
    __shared__ int s[1024];
    int t = threadIdx.x, i = blockIdx.x * 1024 + t;
    int pad = 0;
    if (i < n) {
        unsigned cnt = 0, dsum = 0;
        union { unsigned char b[8]; uint2 u2; } offs;
#pragma unroll
        for (int k = 0; k < 8; ++k) {
            unsigned v = packed8[(size_t)k * n + i];
            offs.b[k] = (unsigned char)cnt;
            cnt += (v >> CNT_SHIFT);
            dsum += (v & DEG_MASK);
        }
        float d = 1.0f + (float)dsum * (1.0f / DSCALE);
        dinv[i] = rsqrtf(d);
        reinterpret_cast<uint2*>(off8)[i] = offs.u2;
        pad = (int)((cnt + 3u) & ~3u);
        padcnt[i] = pad;
    }
    s[t] = pad;
    __syncthreads();
    for (int off = 512; off > 0; off >>= 1) {
        if (t < off) s[t] += s[t + off];
        __syncthreads();
    }
    if (t == 0) bsum[blockIdx.x] = s[0];
}

__global__ void scan2_k(int* __restrict__ bsum, int nb, int* __restrict__ rp, int n) {
    if (blockIdx.x == 0 && threadIdx.x == 0) {
        int acc = 0;
        for (int b = 0; b < nb; ++b) { int v = bsum[b]; bsum[b] = acc; acc += v; }
        rp[n] = acc;
    }
}

__global__ __launch_bounds__(1024) void scan3_k(const int* __restrict__ padcnt,
                                                const int* __restrict__ bsum,
                                                int* __restrict__ rp, int n) {
    __shared__ int s[1024];
    int t = threadIdx.x, i = blockIdx.x * 1024 + t;
    int v = (i < n) ? padcnt[i] : 0;
    s[t] = v;
    __syncthreads();
    for (int off = 1; off < 1024; off <<= 1) {
        int u = (t >= off) ? s[t - off] : 0;
        __syncthreads();
        s[t] += u;
        __syncthreads();
    }
    if (i < n) rp[i] = bsum[blockIdx.x] + s[t] - v;
}

// ---- fill CSR: XCD-binned by destination range, no atomics ------------
__global__ __launch_bounds__(256) void fill_k(const int* __restrict__ row,
                                              const int* __restrict__ col,
                                              const float* __restrict__ ew,
                                              const float* __restrict__ dinv,
                                              const int* __restrict__ rp,
                                              const unsigned short* __restrict__ rank16,
                                              const unsigned char* __restrict__ off8,
                                              unsigned* __restrict__ edges,
                                              int e, int n) {
    int xcd = blockIdx.x & 7;
    int lo = (int)(((long long)n * xcd) >> 3);
    int hi = (int)(((long long)n * (xcd + 1)) >> 3);
    int nblk = gridDim.x >> 3;
    int stride = nblk * 256;
    for (int i = (blockIdx.x >> 3) * 256 + threadIdx.x; i < e; i += stride) {
        int c = col[i];
        if (c < lo || c >= hi) continue;
        int r = row[i];
        float nw = (1.0f - ALPHA) * dinv[r] * ew[i] * dinv[c];
        union { __half h; unsigned short u; } cv;
        cv.h = __float2half(nw);
        unsigned short rk = rank16[i];
        int pos = rp[c] + (int)off8[c * 8 + (rk >> 8)] + (int)(rk & 0xFFu);
        edges[pos] = ((unsigned)cv.u << 17) | (unsigned)r;
    }
}

// ---- W^T fp16 precompute for input GEMM (padded K=320) ----------------
__global__ void wt_k(const float* __restrict__ Win, f16* __restrict__ Wt) {
    int i = blockIdx.x * blockDim.x + threadIdx.x;  // 64*320
    if (i < 64 * 320) {
        int c = i / 320, k = i - c * 320;
        Wt[i] = (k < FIN) ? (f16)Win[k * 64 + c] : (f16)0.0f;
    }
}

// ---- input GEMM: x0h = relu(x @ W_in + b_in) via MFMA fp16 ------------
__global__ __launch_bounds__(256) void gemm_in_k(const float* __restrict__ x,
                                                 const f16* __restrict__ Wt,
                                                 const float* __restrict__ bin,
                                                 __half* __restrict__ x0h, int n) {
    __shared__ f16 As[64 * 72];  // x chunk tile (64 nodes x 64 k), pad 8
    int t = threadIdx.x, lane = t & 63, wv = t >> 6;
    int node0 = blockIdx.x * 64;
    int lr = lane & 15, kg = lane >> 4;
    f32x4 acc0 = {0, 0, 0, 0}, acc1 = {0, 0, 0, 0}, acc2 = {0, 0, 0, 0}, acc3 = {0, 0, 0, 0};
    int fi = t & 15;
    for (int c = 0; c < 5; ++c) {
        __syncthreads();
#pragma unroll
        for (int it = 0; it < 4; ++it) {
            int row = (t >> 4) + it * 16;
            int rr = node0 + row;
            rr = (rr < n) ? rr : (n - 1);
            int kbase = c * 64 + fi * 4;
            float4 v = make_float4(0.f, 0.f, 0.f, 0.f);
            if (kbase < FIN)
                v = *reinterpret_cast<const float4*>(x + (size_t)rr * FIN + kbase);
            union { float2 f2; f16 h[4]; } u;
            u.h[0] = (f16)v.x; u.h[1] = (f16)v.y; u.h[2] = (f16)v.z; u.h[3] = (f16)v.w;
            *reinterpret_cast<float2*>(As + row * 72 + fi * 4) = u.f2;
        }
        __syncthreads();
#pragma unroll
        for (int ks = 0; ks < 2; ++ks) {
            f16x8 a = *(const f16x8*)(As + (wv * 16 + lr) * 72 + ks * 32 + kg * 8);
            const f16* wb = Wt + c * 64 + ks * 32 + kg * 8;
            f16x8 b0 = *(const f16x8*)(wb + (0 * 16 + lr) * 320);
            f16x8 b1 = *(const f16x8*)(wb + (1 * 16 + lr) * 320);
            f16x8 b2 = *(const f16x8*)(wb + (2 * 16 + lr) * 320);
            f16x8 b3 = *(const f16x8*)(wb + (3 * 16 + lr) * 320);
            acc0 = __builtin_amdgcn_mfma_f32_16x16x32_f16(a, b0, acc0, 0, 0, 0);
            acc1 = __builtin_amdgcn_mfma_f32_16x16x32_f16(a, b1, acc1, 0, 0, 0);
            acc2 = __builtin_amdgcn_mfma_f32_16x16x32_f16(a, b2, acc2, 0, 0, 0);
            acc3 = __builtin_amdgcn_mfma_f32_16x16x32_f16(a, b3, acc3, 0, 0, 0);
        }
    }
    float bi0 = bin[0 * 16 + lr], bi1 = bin[1 * 16 + lr];
    float bi2 = bin[2 * 16 + lr], bi3 = bin[3 * 16 + lr];
    f16 ov[4][4];
#pragma unroll
    for (int r = 0; r < 4; ++r) {
        ov[0][r] = (f16)fmaxf(acc0[r] + bi0, 0.f);
        ov[1][r] = (f16)fmaxf(acc1[r] + bi1, 0.f);
        ov[2][r] = (f16)fmaxf(acc2[r] + bi2, 0.f);
        ov[3][r] = (f16)fmaxf(acc3[r] + bi3, 0.f);
    }
    __syncthreads();
#pragma unroll
    for (int cg = 0; cg < 4; ++cg)
#pragma unroll
        for (int r = 0; r < 4; ++r)
            As[(wv * 16 + kg * 4 + r) * 72 + cg * 16 + lr] = ov[cg][r];
    __syncthreads();
#pragma unroll
    for (int it = 0; it < 2; ++it) {
        int idx = t + it * 256;
        int row = idx >> 3, ch = idx & 7;
        int node = node0 + row;
        if (node < n)
            ((float4*)(x0h + (size_t)node * 64))[ch] =
                *reinterpret_cast<const float4*>(As + row * 72 + ch * 8);
    }
}

// ---- fused layer: uint4 edge load + 4-wide gather -> LDS z -> MFMA ----
__global__ __launch_bounds__(256) void layer_k(const int* __restrict__ rp,
                                               const unsigned* __restrict__ edges,
                                               const float* __restrict__ dinv,
                                               const __half* __restrict__ x0h,
                                               const __half* __restrict__ hin,
                                               __half* __restrict__ hout,
                                               const float* __restrict__ Wl,
                                               float beta, int n) {
    __shared__ f16 As[64 * 72];  // z tile
    __shared__ f16 Bs[64 * 72];  // W^T tile
    int t = threadIdx.x, lane = t & 63, wv = t >> 6;
    int node0 = blockIdx.x * 64;
    for (int i = t; i < 4096; i += 256) {
        int k = i >> 6, c = i & 63;
        Bs[c * 72 + k] = (f16)Wl[i];
    }
    int g = lane >> 3, c8 = lane & 7;
#pragma unroll
    for (int pass = 0; pass < 2; ++pass) {
        int row = pass * 32 + wv * 8 + g;
        int node = node0 + row;
        int nd = (node < n) ? node : (n - 1);
        int j = rp[nd], end = (node < n) ? rp[nd + 1] : j;
        float a0[8], a1[8], a2[8], a3[8];
#pragma unroll
        for (int i = 0; i < 8; ++i) { a0[i] = 0.f; a1[i] = 0.f; a2[i] = 0.f; a3[i] = 0.f; }
        while (__any(j < end)) {
            bool v = j < end;
            uint4 e4 = *reinterpret_cast<const uint4*>(edges + (v ? j : 0));
            float w0 = v ? wdec(e4.x) : 0.f;
            float w1 = v ? wdec(e4.y) : 0.f;
            float w2 = v ? wdec(e4.z) : 0.f;
            float w3 = v ? wdec(e4.w) : 0.f;
            float4 r0 = ((const float4*)(hin + (size_t)(e4.x & 0x1FFFF) * 64))[c8];
            float4 r1 = ((const float4*)(hin + (size_t)(e4.y & 0x1FFFF) * 64))[c8];
            float4 r2 = ((const float4*)(hin + (size_t)(e4.z & 0x1FFFF) * 64))[c8];
            float4 r3 = ((const float4*)(hin + (size_t)(e4.w & 0x1FFFF) * 64))[c8];
            float f0[8], f1[8], f2[8], f3[8];
            unpack8(r0, f0);
            unpack8(r1, f1);
            unpack8(r2, f2);
            unpack8(r3, f3);
#pragma unroll
            for (int i = 0; i < 8; ++i) {
                a0[i] = fmaf(w0, f0[i], a0[i]);
                a1[i] = fmaf(w1, f1[i], a1[i]);
                a2[i] = fmaf(w2, f2[i], a2[i]);
                a3[i] = fmaf(w3, f3[i], a3[i]);
            }
            j += 4;
        }
        float di = dinv[nd];
        float c1 = (1.0f - ALPHA) * di * di;
        float4 hs4 = ((const float4*)(hin + (size_t)nd * 64))[c8];
        float4 xs4 = ((const float4*)(x0h + (size_t)nd * 64))[c8];
        float hf[8], xf[8];
        unpack8(hs4, hf);
        unpack8(xs4, xf);
        f16x8 zv8;
#pragma unroll
        for (int i = 0; i < 8; ++i)
            zv8[i] = (f16)fmaf(ALPHA, xf[i],
                               fmaf(c1, hf[i], (a0[i] + a1[i]) + (a2[i] + a3[i])));
        *(f16x8*)(As + row * 72 + c8 * 8) = zv8;
    }
    __syncthreads();
    int lr = lane & 15, kg = lane >> 4;
    f32x4 acc0 = {0, 0, 0, 0}, acc1 = {0, 0, 0, 0}, acc2 = {0, 0, 0, 0}, acc3 = {0, 0, 0, 0};
    f16x8 af0 = *(const f16x8*)(As + (wv * 16 + lr) * 72 + kg * 8);
    f16x8 af1 = *(const f16x8*)(As + (wv * 16 + lr) * 72 + 32 + kg * 8);
    {
        f16x8 b0 = *(const f16x8*)(Bs + (0 * 16 + lr) * 72 + kg * 8);
        f16x8 b1 = *(const f16x8*)(Bs + (0 * 16 + lr) * 72 + 32 + kg * 8);
        acc0 = __builtin_amdgcn_mfma_f32_16x16x32_f16(af0, b0, acc0, 0, 0, 0);
        acc0 = __builtin_amdgcn_mfma_f32_16x16x32_f16(af1, b1, acc0, 0, 0, 0);
    }
    {
        f16x8 b0 = *(const f16x8*)(Bs + (1 * 16 + lr) * 72 + kg * 8);
        f16x8 b1 = *(const f16x8*)(Bs + (1 * 16 + lr) * 72 + 32 + kg * 8);
        acc1 = __builtin_amdgcn_mfma_f32_16x16x32_f16(af0, b0, acc1, 0, 0, 0);
        acc1 = __builtin_amdgcn_mfma_f32_16x16x32_f16(af1, b1, acc1, 0, 0, 0);
    }
    {
        f16x8 b0 = *(const f16x8*)(Bs + (2 * 16 + lr) * 72 + kg * 8);
        f16x8 b1 = *(const f16x8*)(Bs + (2 * 16 + lr) * 72 + 32 + kg * 8);
        acc2 = __builtin_amdgcn_mfma_f32_16x16x32_f16(af0, b0, acc2, 0, 0, 0);
        acc2 = __builtin_amdgcn_mfma_f32_16x16x32_f16(af1, b1, acc2, 0, 0, 0);
    }
    {
        f16x8 b0 = *(const f16x8*)(Bs + (3 * 16 + lr) * 72 + kg * 8);
        f16x8 b1 = *(const f16x8*)(Bs + (3 * 16 + lr) * 72 + 32 + kg * 8);
        acc3 = __builtin_amdgcn_mfma_f32_16x16x32_f16(af0, b0, acc3, 0, 0, 0);
        acc3 = __builtin_amdgcn_mfma_f32_16x16x32_f16(af1, b1, acc3, 0, 0, 0);
    }
    float omb = 1.0f - beta;
    f16 ov[4][4];
#pragma unroll
    for (int cg = 0; cg < 4; ++cg) {
        f32x4 acc = (cg == 0) ? acc0 : (cg == 1) ? acc1 : (cg == 2) ? acc2 : acc3;
        int col = cg * 16 + lr;
#pragma unroll
        for (int r = 0; r < 4; ++r) {
            float zv = (float)As[(wv * 16 + kg * 4 + r) * 72 + col];
            ov[cg][r] = (f16)fmaxf(fmaf(beta, acc[r], omb * zv), 0.f);
        }
    }
    __syncthreads();
#pragma unroll
    for (int cg = 0; cg < 4; ++cg)
#pragma unroll
        for (int r = 0; r < 4; ++r)
            As[(wv * 16 + kg * 4 + r) * 72 + cg * 16 + lr] = ov[cg][r];
    __syncthreads();
#pragma unroll
    for (int it = 0; it < 2; ++it) {
        int idx = t + it * 256;
        int row = idx >> 3, ch = idx & 7;
        int node = node0 + row;
        if (node < n)
            ((float4*)(hout + (size_t)node * 64))[ch] =
                *reinterpret_cast<const float4*>(As + row * 72 + ch * 8);
    }
}

// ---- output GEMM: out = h @ W_out + b_out -----------------------------
__global__ __launch_bounds__(256) void gemm_out_k(const __half* __restrict__ h,
                                                  const float* __restrict__ Wout,
                                                  const float* __restrict__ bout,
                                                  float* __restrict__ out, int n) {
    __shared__ float hs[64][65];
    __shared__ float Ws[64 * NOUT];
    __shared__ float bs[NOUT];
    int t = threadIdx.x;
    for (int i = t; i < 64 * NOUT; i += 256) Ws[i] = Wout[i];
    if (t < NOUT) bs[t] = bout[t];
    int base = blockIdx.x * 64;
    int lim = min(64, n - base);
    for (int i = t; i < 64 * 32; i += 256) {
        int r = i >> 5, c2 = (i & 31) * 2;
        float2 v = make_float2(0.f, 0.f);
        if (r < lim) {
            __half2 hv = reinterpret_cast<const __half2*>(
                h + (size_t)(base + r) * 64)[i & 31];
            v = __half22float2(hv);
        }
        hs[r][c2] = v.x;
        hs[r][c2 + 1] = v.y;
    }
    __syncthreads();
#pragma unroll
    for (int q = 0; q < 5; ++q) {
        int of = t + 256 * q;
        int nd = of / NOUT, o = of - nd * NOUT;
        float acc = bs[o];
#pragma unroll
        for (int k = 0; k < 64; ++k) acc = fmaf(hs[nd][k], Ws[k * NOUT + o], acc);
        if (nd < lim) out[(size_t)(base + nd) * NOUT + o] = acc;
    }
}

extern "C" void kernel_launch(void* const* d_in, const int* in_sizes, int n_in,
                              void* d_out, int out_size, void* d_ws, size_t ws_size,
                              hipStream_t stream) {
    const float* x    = (const float*)d_in[0];
    const int*   ei   = (const int*)d_in[1];
    const float* ew   = (const float*)d_in[2];
    const float* Win  = (const float*)d_in[3];
    const float* bin  = (const float*)d_in[4];
    const float* cw   = (const float*)d_in[5];
    const float* Wout = (const float*)d_in[6];
    const float* bout = (const float*)d_in[7];

    const int n = in_sizes[0] / FIN;          // 100000
    const int e = in_sizes[2];                // 1600000
    const int L = in_sizes[5] / (HID * HID);  // 8
    const int* row = ei;
    const int* col = ei + e;
    const int epadmax = e + 3 * n + 64;

    size_t off = 0;
    auto alloc = [&](size_t bytes) -> char* {
        char* q = (char*)d_ws + off;
        off = (off + bytes + 255) & ~(size_t)255;
        return q;
    };
    __half* x0h  = (__half*)alloc((size_t)n * HID * 2);
    __half* hA   = (__half*)alloc((size_t)n * HID * 2);
    __half* hB   = (__half*)alloc((size_t)n * HID * 2);
    unsigned* edges = (unsigned*)alloc((size_t)epadmax * 4);
    unsigned short* rank16 = (unsigned short*)alloc((size_t)e * 2);
    unsigned* packed8 = (unsigned*)alloc((size_t)8 * n * 4);
    unsigned char* off8 = (unsigned char*)alloc((size_t)n * 8);
    float* dinv  = (float*)alloc((size_t)n * 4);
    int*   padcnt= (int*)alloc((size_t)n * 4);
    int*   rp    = (int*)alloc((size_t)(n + 1) * 4);
    int*   bsum  = (int*)alloc(1024 * 4);
    f16*   Wt    = (f16*)alloc((size_t)64 * 320 * 2);

    const int nb = (n + 1023) / 1024;
    const int ntile = (n + 63) / 64;

    zero_k<<<(8 * n + 255) / 256, 256, 0, stream>>>(packed8, 8 * n);
    zero_k<<<(epadmax + 255) / 256, 256, 0, stream>>>(edges, epadmax);
    accum_k<<<(e + 255) / 256, 256, 0, stream>>>(col, ew, packed8, rank16, e, n);
    unpackscan_k<<<nb, 1024, 0, stream>>>(packed8, dinv, off8, padcnt, bsum, n);
    scan2_k<<<1, 1, 0, stream>>>(bsum, nb, rp, n);
    scan3_k<<<nb, 1024, 0, stream>>>(padcnt, bsum, rp, n);
    fill_k<<<1024, 256, 0, stream>>>(row, col, ew, dinv, rp, rank16, off8, edges, e, n);

    wt_k<<<(64 * 320 + 255) / 256, 256, 0, stream>>>(Win, Wt);
    gemm_in_k<<<ntile, 256, 0, stream>>>(x, Wt, bin, x0h, n);

    const __half* hin = x0h;
    __half* hout = hA;
    for (int l = 0; l < L; ++l) {
        float beta = (float)log(0.5 / (double)(l + 1) + 1.0);
        layer_k<<<ntile, 256, 0, stream>>>(rp, edges, dinv, x0h, hin, hout,
                                           cw + (size_t)l * HID * HID, beta, n);
        hin = hout;
        hout = (hout == hA) ? hB : hA;
    }
    gemm_out_k<<<(n + 63) / 64, 256, 0, stream>>>(hin, Wout, bout, (float*)d_out, n);
}

// Round 9
// 492.044 us; speedup vs baseline: 1.0640x; 1.0640x over previous
//
#include <hip/hip_runtime.h>
#include <hip/hip_fp16.h>
#include <math.h>

// GCNII forward: N=100000, E=1.6M, F_IN=300, H=64, OUT=20, L=8
// Round 9: exec-masked gather (no dummy traffic), reg-staged double-buffered
// input GEMM, wave-parallel scan2, packed 8B edge records, output GEMM fused
// into the last layer via a second MFMA pass.

#define HID 64
#define FIN 300
#define NOUT 20
#define ALPHA 0.1f
#define DSCALE 262144.0f   // 2^18 fixed-point scale for weighted degree
#define CNT_SHIFT 25
#define DEG_MASK 0x1FFFFFFu

typedef _Float16 f16;
typedef f16 f16x8 __attribute__((ext_vector_type(8)));
typedef float f32x4 __attribute__((ext_vector_type(4)));

// ---- helpers -----------------------------------------------------------
__device__ __forceinline__ float wdec(unsigned v) {
    union { unsigned short u; __half h; } c;
    c.u = (unsigned short)(v >> 17);
    return __half2float(c.h);
}

__device__ __forceinline__ void unpack8(const float4& v, float* f) {
    const __half2* p = reinterpret_cast<const __half2*>(&v);
#pragma unroll
    for (int i = 0; i < 4; ++i) {
        float2 t = __half22float2(p[i]);
        f[2 * i] = t.x;
        f[2 * i + 1] = t.y;
    }
}

// ---- generic zero ------------------------------------------------------
__global__ void zero_k(unsigned* __restrict__ p, int nwords) {
    int i = blockIdx.x * blockDim.x + threadIdx.x;
    if (i < nwords) p[i] = 0u;
}

// ---- privatized histogram + packed edge record -------------------------
__global__ void accum_k(const int* __restrict__ row, const int* __restrict__ col,
                        const float* __restrict__ w,
                        unsigned* __restrict__ packed8,
                        uint2* __restrict__ rec, int e, int n) {
    int i = blockIdx.x * blockDim.x + threadIdx.x;
    if (i < e) {
        int copy = blockIdx.x & 7;
        int c = col[i], r = row[i];
        float wv = w[i];
        unsigned q = (unsigned)__float2uint_rn(wv * DSCALE);
        unsigned old = atomicAdd(&packed8[(size_t)copy * n + c], (1u << CNT_SHIFT) | q);
        unsigned rank = (old >> CNT_SHIFT) & 0xFFu;
        union { __half h; unsigned short u; } cv;
        cv.h = __float2half(wv);  // w in [0,1) -> bit15 == 0
        rec[i] = make_uint2((unsigned)c | ((unsigned)copy << 17) | (rank << 20),
                            (unsigned)r | ((unsigned)cv.u << 17));
    }
}

// ---- fold 8 copies: dinv, per-copy offsets, padded counts, block sums ---
__global__ __launch_bounds__(1024) void unpackscan_k(const unsigned* __restrict__ packed8,
                                                     float* __restrict__ dinv,
                                                     unsigned char* __restrict__ off8,
                                                     int* __restrict__ padcnt,
                                                     int* __restrict__ bsum, int n) {
    __shared__ int s[1024];
    int t = threadIdx.x, i = blockIdx.x * 1024 + t;
    int pad = 0;
    if (i < n) {
        unsigned cnt = 0, dsum = 0;
        union { unsigned char b[8]; uint2 u2; } offs;
#pragma unroll
        for (int k = 0; k < 8; ++k) {
            unsigned v = packed8[(size_t)k * n + i];
            offs.b[k] = (unsigned char)cnt;
            cnt += (v >> CNT_SHIFT);
            dsum += (v & DEG_MASK);
        }
        float d = 1.0f + (float)dsum * (1.0f / DSCALE);
        dinv[i] = rsqrtf(d);
        reinterpret_cast<uint2*>(off8)[i] = offs.u2;
        pad = (int)((cnt + 3u) & ~3u);
        padcnt[i] = pad;
    }
    s[t] = pad;
    __syncthreads();
    for (int off = 512; off > 0; off >>= 1) {
        if (t < off) s[t] += s[t + off];
        __syncthreads();
    }
    if (t == 0) bsum[blockIdx.x] = s[0];
}

// ---- wave-parallel exclusive scan of block sums (nb <= 128) -----------
__global__ void scan2_k(int* __restrict__ bsum, int nb, int* __restrict__ rp, int n) {
    int lane = threadIdx.x;  // 64 threads
    int acc = 0;
    for (int base = 0; base < nb; base += 64) {
        int idx = base + lane;
        int orig = (idx < nb) ? bsum[idx] : 0;
        int v = orig;
#pragma unroll
        for (int d = 1; d < 64; d <<= 1) {
            int u = __shfl_up(v, d);
            if (lane >= d) v += u;
        }
        if (idx < nb) bsum[idx] = acc + v - orig;
        acc += __shfl(v, 63);
    }
    if (lane == 0) rp[n] = acc;
}

__global__ __launch_bounds__(1024) void scan3_k(const int* __restrict__ padcnt,
                                                const int* __restrict__ bsum,
                                                int* __restrict__ rp, int n) {
    __shared__ int s[1024];
    int t = threadIdx.x, i = blockIdx.x * 1024 + t;
    int v = (i < n) ? padcnt[i] : 0;
    s[t] = v;
    __syncthreads();
    for (int off = 1; off < 1024; off <<= 1) {
        int u = (t >= off) ? s[t - off] : 0;
        __syncthreads();
        s[t] += u;
        __syncthreads();
    }
    if (i < n) rp[i] = bsum[blockIdx.x] + s[t] - v;
}

// ---- fill CSR: XCD-binned, streams packed records, no atomics ---------
__global__ __launch_bounds__(256) void fill_k(const uint2* __restrict__ rec,
                                              const float* __restrict__ dinv,
                                              const int* __restrict__ rp,
                                              const unsigned char* __restrict__ off8,
                                              unsigned* __restrict__ edges,
                                              int e, int n) {
    int xcd = blockIdx.x & 7;
    int lo = (int)(((long long)n * xcd) >> 3);
    int hi = (int)(((long long)n * (xcd + 1)) >> 3);
    int nblk = gridDim.x >> 3;
    int stride = nblk * 256;
    for (int i = (blockIdx.x >> 3) * 256 + threadIdx.x; i < e; i += stride) {
        uint2 rc = rec[i];
        int c = (int)(rc.x & 0x1FFFFu);
        if (c < lo || c >= hi) continue;
        int r = (int)(rc.y & 0x1FFFFu);
        union { unsigned short u; __half h; } ev;
        ev.u = (unsigned short)(rc.y >> 17);
        float nw = (1.0f - ALPHA) * dinv[r] * __half2float(ev.h) * dinv[c];
        union { __half h; unsigned short u; } cv;
        cv.h = __float2half(nw);
        int copy = (int)((rc.x >> 17) & 7u);
        int rank = (int)((rc.x >> 20) & 0xFFu);
        int pos = rp[c] + (int)off8[c * 8 + copy] + rank;
        edges[pos] = ((unsigned)cv.u << 17) | (unsigned)r;
    }
}

// ---- W^T fp16 precompute for input GEMM (padded K=320) ----------------
__global__ void wt_k(const float* __restrict__ Win, f16* __restrict__ Wt) {
    int i = blockIdx.x * blockDim.x + threadIdx.x;  // 64*320
    if (i < 64 * 320) {
        int c = i / 320, k = i - c * 320;
        Wt[i] = (k < FIN) ? (f16)Win[k * 64 + c] : (f16)0.0f;
    }
}

// ---- input GEMM: x0h = relu(x @ W_in + b_in) via MFMA fp16 ------------
// reg-staged double buffer: chunk c+1 loads fly under chunk c's MFMA.
__global__ __launch_bounds__(256) void gemm_in_k(const float* __restrict__ x,
                                                 const f16* __restrict__ Wt,
                                                 const float* __restrict__ bin,
                                                 __half* __restrict__ x0h, int n) {
    __shared__ f16 As[64 * 72];
    int t = threadIdx.x, lane = t & 63, wv = t >> 6;
    int node0 = blockIdx.x * 64;
    int lr = lane & 15, kg = lane >> 4;
    int fi = t & 15, rowbase = t >> 4;
    f32x4 acc0 = {0, 0, 0, 0}, acc1 = {0, 0, 0, 0}, acc2 = {0, 0, 0, 0}, acc3 = {0, 0, 0, 0};
    float4 xr[4];

    auto loadchunk = [&](int c) {
#pragma unroll
        for (int it = 0; it < 4; ++it) {
            int row = rowbase + it * 16;
            int rr = node0 + row;
            rr = (rr < n) ? rr : (n - 1);
            int kbase = c * 64 + fi * 4;
            xr[it] = make_float4(0.f, 0.f, 0.f, 0.f);
            if (kbase < FIN)
                xr[it] = *reinterpret_cast<const float4*>(x + (size_t)rr * FIN + kbase);
        }
    };
    loadchunk(0);

    for (int c = 0; c < 5; ++c) {
        __syncthreads();
#pragma unroll
        for (int it = 0; it < 4; ++it) {
            int row = rowbase + it * 16;
            union { float2 f2; f16 h[4]; } u;
            u.h[0] = (f16)xr[it].x; u.h[1] = (f16)xr[it].y;
            u.h[2] = (f16)xr[it].z; u.h[3] = (f16)xr[it].w;
            *reinterpret_cast<float2*>(As + row * 72 + fi * 4) = u.f2;
        }
        __syncthreads();
        if (c < 4) loadchunk(c + 1);
#pragma unroll
        for (int ks = 0; ks < 2; ++ks) {
            f16x8 a = *(const f16x8*)(As + (wv * 16 + lr) * 72 + ks * 32 + kg * 8);
            const f16* wb = Wt + c * 64 + ks * 32 + kg * 8;
            f16x8 b0 = *(const f16x8*)(wb + (0 * 16 + lr) * 320);
            f16x8 b1 = *(const f16x8*)(wb + (1 * 16 + lr) * 320);
            f16x8 b2 = *(const f16x8*)(wb + (2 * 16 + lr) * 320);
            f16x8 b3 = *(const f16x8*)(wb + (3 * 16 + lr) * 320);
            acc0 = __builtin_amdgcn_mfma_f32_16x16x32_f16(a, b0, acc0, 0, 0, 0);
            acc1 = __builtin_amdgcn_mfma_f32_16x16x32_f16(a, b1, acc1, 0, 0, 0);
            acc2 = __builtin_amdgcn_mfma_f32_16x16x32_f16(a, b2, acc2, 0, 0, 0);
            acc3 = __builtin_amdgcn_mfma_f32_16x16x32_f16(a, b3, acc3, 0, 0, 0);
        }
    }
    float bi0 = bin[0 * 16 + lr], bi1 = bin[1 * 16 + lr];
    float bi2 = bin[2 * 16 + lr], bi3 = bin[3 * 16 + lr];
    f16 ov[4][4];
#pragma unroll
    for (int r = 0; r < 4; ++r) {
        ov[0][r] = (f16)fmaxf(acc0[r] + bi0, 0.f);
        ov[1][r] = (f16)fmaxf(acc1[r] + bi1, 0.f);
        ov[2][r] = (f16)fmaxf(acc2[r] + bi2, 0.f);
        ov[3][r] = (f16)fmaxf(acc3[r] + bi3, 0.f);
    }
    __syncthreads();
#pragma unroll
    for (int cg = 0; cg < 4; ++cg)
#pragma unroll
        for (int r = 0; r < 4; ++r)
            As[(wv * 16 + kg * 4 + r) * 72 + cg * 16 + lr] = ov[cg][r];
    __syncthreads();
#pragma unroll
    for (int it = 0; it < 2; ++it) {
        int idx = t + it * 256;
        int row = idx >> 3, ch = idx & 7;
        int node = node0 + row;
        if (node < n)
            ((float4*)(x0h + (size_t)node * 64))[ch] =
                *reinterpret_cast<const float4*>(As + row * 72 + ch * 8);
    }
}

// ---- fused layer: masked uint4 gather -> LDS z -> MFMA (+fused out) ----
__global__ __launch_bounds__(256) void layer_k(const int* __restrict__ rp,
                                               const unsigned* __restrict__ edges,
                                               const float* __restrict__ dinv,
                                               const __half* __restrict__ x0h,
                                               const __half* __restrict__ hin,
                                               __half* __restrict__ hout,
                                               const float* __restrict__ Wl,
                                               float beta, int n,
                                               const float* __restrict__ Wout,
                                               const float* __restrict__ bout,
                                               float* __restrict__ out) {
    __shared__ f16 As[64 * 72];  // z tile / h tile
    __shared__ f16 Bs[64 * 72];  // W^T tile (reused for Wout^T)
    int t = threadIdx.x, lane = t & 63, wv = t >> 6;
    int node0 = blockIdx.x * 64;
    for (int i = t; i < 4096; i += 256) {
        int k = i >> 6, c = i & 63;
        Bs[c * 72 + k] = (f16)Wl[i];
    }
    int g = lane >> 3, c8 = lane & 7;
#pragma unroll
    for (int pass = 0; pass < 2; ++pass) {
        int row = pass * 32 + wv * 8 + g;
        int node = node0 + row;
        int nd = (node < n) ? node : (n - 1);
        int j = rp[nd], end = (node < n) ? rp[nd + 1] : j;
        float a0[8], a1[8], a2[8], a3[8];
#pragma unroll
        for (int i = 0; i < 8; ++i) { a0[i] = 0.f; a1[i] = 0.f; a2[i] = 0.f; a3[i] = 0.f; }
        while (__any(j < end)) {
            if (j < end) {  // group-uniform: finished groups issue NO memory ops
                uint4 e4 = *reinterpret_cast<const uint4*>(edges + j);
                float w0 = wdec(e4.x), w1 = wdec(e4.y), w2 = wdec(e4.z), w3 = wdec(e4.w);
                float4 r0 = ((const float4*)(hin + (size_t)(e4.x & 0x1FFFF) * 64))[c8];
                float4 r1 = ((const float4*)(hin + (size_t)(e4.y & 0x1FFFF) * 64))[c8];
                float4 r2 = ((const float4*)(hin + (size_t)(e4.z & 0x1FFFF) * 64))[c8];
                float4 r3 = ((const float4*)(hin + (size_t)(e4.w & 0x1FFFF) * 64))[c8];
                float f0[8], f1[8], f2[8], f3[8];
                unpack8(r0, f0);
                unpack8(r1, f1);
                unpack8(r2, f2);
                unpack8(r3, f3);
#pragma unroll
                for (int i = 0; i < 8; ++i) {
                    a0[i] = fmaf(w0, f0[i], a0[i]);
                    a1[i] = fmaf(w1, f1[i], a1[i]);
                    a2[i] = fmaf(w2, f2[i], a2[i]);
                    a3[i] = fmaf(w3, f3[i], a3[i]);
                }
            }
            j += 4;
        }
        float di = dinv[nd];
        float c1 = (1.0f - ALPHA) * di * di;
        float4 hs4 = ((const float4*)(hin + (size_t)nd * 64))[c8];
        float4 xs4 = ((const float4*)(x0h + (size_t)nd * 64))[c8];
        float hf[8], xf[8];
        unpack8(hs4, hf);
        unpack8(xs4, xf);
        f16x8 zv8;
#pragma unroll
        for (int i = 0; i < 8; ++i)
            zv8[i] = (f16)fmaf(ALPHA, xf[i],
                               fmaf(c1, hf[i], (a0[i] + a1[i]) + (a2[i] + a3[i])));
        *(f16x8*)(As + row * 72 + c8 * 8) = zv8;
    }
    __syncthreads();
    int lr = lane & 15, kg = lane >> 4;
    f32x4 acc0 = {0, 0, 0, 0}, acc1 = {0, 0, 0, 0}, acc2 = {0, 0, 0, 0}, acc3 = {0, 0, 0, 0};
    f16x8 af0 = *(const f16x8*)(As + (wv * 16 + lr) * 72 + kg * 8);
    f16x8 af1 = *(const f16x8*)(As + (wv * 16 + lr) * 72 + 32 + kg * 8);
    {
        f16x8 b0 = *(const f16x8*)(Bs + (0 * 16 + lr) * 72 + kg * 8);
        f16x8 b1 = *(const f16x8*)(Bs + (0 * 16 + lr) * 72 + 32 + kg * 8);
        acc0 = __builtin_amdgcn_mfma_f32_16x16x32_f16(af0, b0, acc0, 0, 0, 0);
        acc0 = __builtin_amdgcn_mfma_f32_16x16x32_f16(af1, b1, acc0, 0, 0, 0);
    }
    {
        f16x8 b0 = *(const f16x8*)(Bs + (1 * 16 + lr) * 72 + kg * 8);
        f16x8 b1 = *(const f16x8*)(Bs + (1 * 16 + lr) * 72 + 32 + kg * 8);
        acc1 = __builtin_amdgcn_mfma_f32_16x16x32_f16(af0, b0, acc1, 0, 0, 0);
        acc1 = __builtin_amdgcn_mfma_f32_16x16x32_f16(af1, b1, acc1, 0, 0, 0);
    }
    {
        f16x8 b0 = *(const f16x8*)(Bs + (2 * 16 + lr) * 72 + kg * 8);
        f16x8 b1 = *(const f16x8*)(Bs + (2 * 16 + lr) * 72 + 32 + kg * 8);
        acc2 = __builtin_amdgcn_mfma_f32_16x16x32_f16(af0, b0, acc2, 0, 0, 0);
        acc2 = __builtin_amdgcn_mfma_f32_16x16x32_f16(af1, b1, acc2, 0, 0, 0);
    }
    {
        f16x8 b0 = *(const f16x8*)(Bs + (3 * 16 + lr) * 72 + kg * 8);
        f16x8 b1 = *(const f16x8*)(Bs + (3 * 16 + lr) * 72 + 32 + kg * 8);
        acc3 = __builtin_amdgcn_mfma_f32_16x16x32_f16(af0, b0, acc3, 0, 0, 0);
        acc3 = __builtin_amdgcn_mfma_f32_16x16x32_f16(af1, b1, acc3, 0, 0, 0);
    }
    float omb = 1.0f - beta;
    f16 ov[4][4];
#pragma unroll
    for (int cg = 0; cg < 4; ++cg) {
        f32x4 acc = (cg == 0) ? acc0 : (cg == 1) ? acc1 : (cg == 2) ? acc2 : acc3;
        int col = cg * 16 + lr;
#pragma unroll
        for (int r = 0; r < 4; ++r) {
            float zv = (float)As[(wv * 16 + kg * 4 + r) * 72 + col];
            ov[cg][r] = (f16)fmaxf(fmaf(beta, acc[r], omb * zv), 0.f);
        }
    }
    __syncthreads();
#pragma unroll
    for (int cg = 0; cg < 4; ++cg)
#pragma unroll
        for (int r = 0; r < 4; ++r)
            As[(wv * 16 + kg * 4 + r) * 72 + cg * 16 + lr] = ov[cg][r];
    __syncthreads();

    if (!Wout) {
        // normal layer: store h tile
#pragma unroll
        for (int it = 0; it < 2; ++it) {
            int idx = t + it * 256;
            int row = idx >> 3, ch = idx & 7;
            int node = node0 + row;
            if (node < n)
                ((float4*)(hout + (size_t)node * 64))[ch] =
                    *reinterpret_cast<const float4*>(As + row * 72 + ch * 8);
        }
    } else {
        // last layer: fused out = h @ W_out + b_out via second MFMA pass
        for (int i = t; i < 32 * 64; i += 256) {
            int c = i >> 6, k = i & 63;
            Bs[c * 72 + k] = (c < NOUT) ? (f16)Wout[k * NOUT + c] : (f16)0.0f;
        }
        __syncthreads();
        f16x8 ha0 = *(const f16x8*)(As + (wv * 16 + lr) * 72 + kg * 8);
        f16x8 ha1 = *(const f16x8*)(As + (wv * 16 + lr) * 72 + 32 + kg * 8);
#pragma unroll
        for (int ct = 0; ct < 2; ++ct) {
            f32x4 oacc = {0, 0, 0, 0};
            f16x8 b0 = *(const f16x8*)(Bs + (ct * 16 + lr) * 72 + kg * 8);
            f16x8 b1 = *(const f16x8*)(Bs + (ct * 16 + lr) * 72 + 32 + kg * 8);
            oacc = __builtin_amdgcn_mfma_f32_16x16x32_f16(ha0, b0, oacc, 0, 0, 0);
            oacc = __builtin_amdgcn_mfma_f32_16x16x32_f16(ha1, b1, oacc, 0, 0, 0);
            int col = ct * 16 + lr;
            if (col < NOUT) {
                float bo = bout[col];
#pragma unroll
                for (int r = 0; r < 4; ++r) {
                    int node = node0 + wv * 16 + kg * 4 + r;
                    if (node < n) out[(size_t)node * NOUT + col] = oacc[r] + bo;
                }
            }
        }
    }
}

extern "C" void kernel_launch(void* const* d_in, const int* in_sizes, int n_in,
                              void* d_out, int out_size, void* d_ws, size_t ws_size,
                              hipStream_t stream) {
    const float* x    = (const float*)d_in[0];
    const int*   ei   = (const int*)d_in[1];
    const float* ew   = (const float*)d_in[2];
    const float* Win  = (const float*)d_in[3];
    const float* bin  = (const float*)d_in[4];
    const float* cw   = (const float*)d_in[5];
    const float* Wout = (const float*)d_in[6];
    const float* bout = (const float*)d_in[7];

    const int n = in_sizes[0] / FIN;          // 100000
    const int e = in_sizes[2];                // 1600000
    const int L = in_sizes[5] / (HID * HID);  // 8
    const int* row = ei;
    const int* col = ei + e;
    const int epadmax = e + 3 * n + 64;

    size_t off = 0;
    auto alloc = [&](size_t bytes) -> char* {
        char* q = (char*)d_ws + off;
        off = (off + bytes + 255) & ~(size_t)255;
        return q;
    };
    __half* x0h  = (__half*)alloc((size_t)n * HID * 2);
    __half* hA   = (__half*)alloc((size_t)n * HID * 2);
    __half* hB   = (__half*)alloc((size_t)n * HID * 2);
    unsigned* edges = (unsigned*)alloc((size_t)epadmax * 4);
    uint2* rec   = (uint2*)alloc((size_t)e * 8);
    unsigned* packed8 = (unsigned*)alloc((size_t)8 * n * 4);
    unsigned char* off8 = (unsigned char*)alloc((size_t)n * 8);
    float* dinv  = (float*)alloc((size_t)n * 4);
    int*   padcnt= (int*)alloc((size_t)n * 4);
    int*   rp    = (int*)alloc((size_t)(n + 1) * 4);
    int*   bsum  = (int*)alloc(1024 * 4);
    f16*   Wt    = (f16*)alloc((size_t)64 * 320 * 2);

    const int nb = (n + 1023) / 1024;
    const int ntile = (n + 63) / 64;

    zero_k<<<(8 * n + 255) / 256, 256, 0, stream>>>(packed8, 8 * n);
    zero_k<<<(epadmax + 255) / 256, 256, 0, stream>>>(edges, epadmax);
    accum_k<<<(e + 255) / 256, 256, 0, stream>>>(row, col, ew, packed8, rec, e, n);
    unpackscan_k<<<nb, 1024, 0, stream>>>(packed8, dinv, off8, padcnt, bsum, n);
    scan2_k<<<1, 64, 0, stream>>>(bsum, nb, rp, n);
    scan3_k<<<nb, 1024, 0, stream>>>(padcnt, bsum, rp, n);
    fill_k<<<1024, 256, 0, stream>>>(rec, dinv, rp, off8, edges, e, n);

    wt_k<<<(64 * 320 + 255) / 256, 256, 0, stream>>>(Win, Wt);
    gemm_in_k<<<ntile, 256, 0, stream>>>(x, Wt, bin, x0h, n);

    const __half* hin = x0h;
    __half* hout = hA;
    for (int l = 0; l < L; ++l) {
        float beta = (float)log(0.5 / (double)(l + 1) + 1.0);
        bool last = (l == L - 1);
        layer_k<<<ntile, 256, 0, stream>>>(rp, edges, dinv, x0h, hin, hout,
                                           cw + (size_t)l * HID * HID, beta, n,
                                           last ? Wout : nullptr,
                                           last ? bout : nullptr,
                                           last ? (float*)d_out : nullptr);
        hin = hout;
        hout = (hout == hA) ? hB : hA;
    }
}